// Round 1
// baseline (661.320 us; speedup 1.0000x reference)
//
#include <hip/hip_runtime.h>
#include <hip/hip_bf16.h>

#define NN  16
#define WT  256
#define TT  2048
#define DIM 256
#define TBT 8      // t-values per block in main kernel (features reuse factor)

__device__ __forceinline__ float silu_f(float x){
    // x * sigmoid(x) == x / (1 + exp(-x)); handles large |x| gracefully
    return x / (1.0f + __expf(-x));
}

__device__ __forceinline__ void fma4(float4& a, float s, const float4& f){
    a.x = fmaf(s, f.x, a.x); a.y = fmaf(s, f.y, a.y);
    a.z = fmaf(s, f.z, a.z); a.w = fmaf(s, f.w, a.w);
}

// ---------------- Kernel A: per-n inclusive cumsum of durations ----------------
__global__ __launch_bounds__(WT) void cumsum_k(const float* __restrict__ dur,
                                               float* __restrict__ ts,
                                               float* __restrict__ te){
    int n = blockIdx.x, w = threadIdx.x;
    __shared__ float s[WT];
    float d = dur[n*WT + w];
    s[w] = d;
    __syncthreads();
    for (int off = 1; off < WT; off <<= 1){
        float v = (w >= off) ? s[w-off] : 0.0f;
        __syncthreads();
        s[w] += v;
        __syncthreads();
    }
    float e = s[w];
    te[n*WT + w] = e;
    ts[n*WT + w] = e - d;
}

// ------- Kernel B: conv(3,256->8)+BN+SiLU both branches, fold into v1/v2 -------
// v2[n,w,j] = sb2_b1[j] - start*sb2_w1[0,j] + end*sb2_w1[1,j] + sum_o right[o]*sb2_w1[2+o,j]
// v1[n,w,p] = sb1_b1[p] - start*sb1_w1[0,p] + end*sb1_w1[1,p] + sum_o left[o]*sb1_w1[2+o,p]
__global__ __launch_bounds__(256) void prep_k(
    const float* __restrict__ feat,
    const float* __restrict__ c1w, const float* __restrict__ c1b,
    const float* __restrict__ g1,  const float* __restrict__ be1,
    const float* __restrict__ m1,  const float* __restrict__ vv1,
    const float* __restrict__ c2w, const float* __restrict__ c2b,
    const float* __restrict__ g2,  const float* __restrict__ be2,
    const float* __restrict__ m2,  const float* __restrict__ vv2,
    const float* __restrict__ sb1w1, const float* __restrict__ sb1b1,
    const float* __restrict__ sb2w1, const float* __restrict__ sb2b1,
    const float* __restrict__ ts, const float* __restrict__ te,
    float* __restrict__ v1o, float* __restrict__ v2o)
{
    int w = blockIdx.x, n = blockIdx.y;
    int tid = threadIdx.x;              // channel c
    const float* fb = feat + (size_t)(n*WT)*DIM;
    float fm = (w > 0)    ? fb[(size_t)(w-1)*DIM + tid] : 0.0f;
    float f0 =              fb[(size_t) w   *DIM + tid];
    float fp = (w < WT-1) ? fb[(size_t)(w+1)*DIM + tid] : 0.0f;

    float pl[8], pr[8];
    #pragma unroll
    for (int o = 0; o < 8; o++){
        const float* wp = c1w + (size_t)(o*DIM + tid)*3;
        pl[o] = fmaf(fm, wp[0], fmaf(f0, wp[1], fp*wp[2]));
        const float* wq = c2w + (size_t)(o*DIM + tid)*3;
        pr[o] = fmaf(fm, wq[0], fmaf(f0, wq[1], fp*wq[2]));
    }
    #pragma unroll
    for (int o = 0; o < 8; o++){
        #pragma unroll
        for (int off = 32; off; off >>= 1){
            pl[o] += __shfl_xor(pl[o], off);
            pr[o] += __shfl_xor(pr[o], off);
        }
    }
    __shared__ float sws[4][16];
    int wave = tid >> 6, lane = tid & 63;
    if (lane == 0){
        #pragma unroll
        for (int o = 0; o < 8; o++){ sws[wave][o] = pl[o]; sws[wave][8+o] = pr[o]; }
    }
    __syncthreads();
    __shared__ float slr[16];   // [0..7]=left(SiLU'd), [8..15]=right
    if (tid < 16){
        float s = sws[0][tid] + sws[1][tid] + sws[2][tid] + sws[3][tid];
        int o = tid & 7; bool isr = tid >= 8;
        float bias = isr ? c2b[o] : c1b[o];
        float mm   = isr ? m2[o]  : m1[o];
        float vv   = isr ? vv2[o] : vv1[o];
        float gg   = isr ? g2[o]  : g1[o];
        float bb   = isr ? be2[o] : be1[o];
        float y = s + bias;
        y = (y - mm) * rsqrtf(vv + 1e-5f);
        y = y * gg + bb;
        slr[tid] = silu_f(y);
    }
    __syncthreads();
    float start = ts[n*WT + w], end = te[n*WT + w];
    if (tid < 16){
        int j = tid;
        float acc = sb2b1[j] - start*sb2w1[j] + end*sb2w1[16 + j];
        #pragma unroll
        for (int o = 0; o < 8; o++) acc = fmaf(slr[8+o], sb2w1[(2+o)*16 + j], acc);
        v2o[(size_t)(n*WT + w)*16 + j] = acc;
    } else if (tid < 18){
        int p = tid - 16;
        float acc = sb1b1[p] - start*sb1w1[p] + end*sb1w1[2 + p];
        #pragma unroll
        for (int o = 0; o < 8; o++) acc = fmaf(slr[o], sb1w1[(2+o)*2 + p], acc);
        v1o[(size_t)(n*WT + w)*2 + p] = acc;
    }
}

// ---------------- Kernel C: scores -> softmax(w) -> weighted sums ----------------
__global__ __launch_bounds__(256) void main_k(
    const float* __restrict__ Tg, const float* __restrict__ feat,
    const float* __restrict__ v1g, const float* __restrict__ v2g,
    const float* __restrict__ sb1w1, const float* __restrict__ sb1w2, const float* __restrict__ sb1b2,
    const float* __restrict__ sb2w1, const float* __restrict__ sb2w2, const float* __restrict__ sb2b2,
    const float* __restrict__ p1w, const float* __restrict__ p1b,
    const float* __restrict__ p2w, const float* __restrict__ p2b,
    float* __restrict__ out)
{
    int n   = blockIdx.y;
    int t0  = blockIdx.x * TBT;
    int tid = threadIdx.x;
    int w   = tid;                       // token index handled by this thread
    int lane = tid & 63, wave = tid >> 6;

    __shared__ float s_w2[16*16];        // sb2_w2[i][j]
    __shared__ float s_u2[16], s_b2[16], s_p2w[16];
    __shared__ float s_u1[2], s_w21[4], s_b21[2];
    __shared__ float s_wsmT[WT][TBT];    // softmax weights, [w][t] for b128 broadcast reads
    __shared__ float s_red[8];
    __shared__ float s_out[4][DIM];

    s_w2[tid] = sb2w2[tid];
    if (tid < 16){
        s_u2[tid]  = sb2w1[tid] - sb2w1[16 + tid];   // S-coeff minus E-coeff
        s_b2[tid]  = sb2b2[tid];
        s_p2w[tid] = p2w[tid];
    } else if (tid < 18){
        int p = tid - 16;
        s_u1[p]  = sb1w1[p] - sb1w1[2 + p];
        s_b21[p] = sb1b2[p];
    } else if (tid < 22){
        s_w21[tid - 18] = sb1w2[tid - 18];
    }
    __syncthreads();

    float v2r[16];
    {
        const float* vp = v2g + (size_t)(n*WT + w)*16;
        #pragma unroll
        for (int k = 0; k < 16; k++) v2r[k] = vp[k];
    }
    float v1r0, v1r1;
    {
        const float* vp = v1g + (size_t)(n*WT + w)*2;
        v1r0 = vp[0]; v1r1 = vp[1];
    }
    float p2bv = p2b[0];

    // ---- per-(w,t) scores and C values ----
    float scores[TBT], c0r[TBT], c1r[TBT];
    #pragma unroll
    for (int ti = 0; ti < TBT; ti++){
        float tcur = Tg[t0 + ti];
        float a1[16];
        #pragma unroll
        for (int j = 0; j < 16; j++) a1[j] = silu_f(fmaf(tcur, s_u2[j], v2r[j]));
        float h2[16];
        #pragma unroll
        for (int j = 0; j < 16; j++) h2[j] = s_b2[j];
        #pragma unroll
        for (int i = 0; i < 16; i++){
            float ai = a1[i];
            #pragma unroll
            for (int j = 0; j < 16; j++) h2[j] = fmaf(ai, s_w2[i*16 + j], h2[j]);
        }
        float sc = p2bv;
        #pragma unroll
        for (int j = 0; j < 16; j++) sc = fmaf(silu_f(h2[j]), s_p2w[j], sc);
        scores[ti] = sc;

        float gl0 = silu_f(fmaf(tcur, s_u1[0], v1r0));
        float gl1 = silu_f(fmaf(tcur, s_u1[1], v1r1));
        c0r[ti] = silu_f(fmaf(gl0, s_w21[0], fmaf(gl1, s_w21[2], s_b21[0])));
        c1r[ti] = silu_f(fmaf(gl0, s_w21[1], fmaf(gl1, s_w21[3], s_b21[1])));
    }

    // ---- softmax over w (per t) + weighted C reduction ----
    float wc0[TBT], wc1[TBT];
    #pragma unroll
    for (int ti = 0; ti < TBT; ti++){
        float m = scores[ti];
        #pragma unroll
        for (int off = 32; off; off >>= 1) m = fmaxf(m, __shfl_xor(m, off));
        if (lane == 0) s_red[wave] = m;
        __syncthreads();
        m = fmaxf(fmaxf(s_red[0], s_red[1]), fmaxf(s_red[2], s_red[3]));
        __syncthreads();

        float e = __expf(scores[ti] - m);
        float s = e;
        #pragma unroll
        for (int off = 32; off; off >>= 1) s += __shfl_xor(s, off);
        if (lane == 0) s_red[wave] = s;
        __syncthreads();
        s = s_red[0] + s_red[1] + s_red[2] + s_red[3];
        __syncthreads();

        float wsm = e / s;
        s_wsmT[w][ti] = wsm;

        float q0 = wsm * c0r[ti], q1 = wsm * c1r[ti];
        #pragma unroll
        for (int off = 32; off; off >>= 1){
            q0 += __shfl_xor(q0, off);
            q1 += __shfl_xor(q1, off);
        }
        if (lane == 0){ s_red[wave] = q0; s_red[4 + wave] = q1; }
        __syncthreads();
        wc0[ti] = s_red[0] + s_red[1] + s_red[2] + s_red[3];
        wc1[ti] = s_red[4] + s_red[5] + s_red[6] + s_red[7];
        __syncthreads();
    }

    // ---- out_r: stream features[n,:,:] once, accumulate TBT output rows ----
    // wave `wid` handles w in {wid, wid+4, ...}; lane handles d-quad = lane*4
    int wid = wave;
    int dq  = lane;
    const float* fbase = feat + (size_t)n*WT*DIM + dq*4;
    float4 acc[TBT];
    #pragma unroll
    for (int i = 0; i < TBT; i++) acc[i] = make_float4(0.f, 0.f, 0.f, 0.f);

    #pragma unroll 4
    for (int w0 = wid; w0 < WT; w0 += 4){
        float4 f = *(const float4*)(fbase + (size_t)w0*DIM);
        const float4* wp = (const float4*)&s_wsmT[w0][0];
        float4 wA = wp[0], wB = wp[1];
        fma4(acc[0], wA.x, f); fma4(acc[1], wA.y, f);
        fma4(acc[2], wA.z, f); fma4(acc[3], wA.w, f);
        fma4(acc[4], wB.x, f); fma4(acc[5], wB.y, f);
        fma4(acc[6], wB.z, f); fma4(acc[7], wB.w, f);
    }

    // ---- epilogue: combine wave partials, add out_l, store ----
    float pw0 = p1w[tid], pw1 = p1w[DIM + tid], pbv = p1b[tid];
    float* orow = out + ((size_t)n*TT + t0)*DIM;
    #pragma unroll
    for (int ti = 0; ti < TBT; ti++){
        __syncthreads();
        *(float4*)&s_out[wid][dq*4] = acc[ti];
        __syncthreads();
        float r = s_out[0][tid] + s_out[1][tid] + s_out[2][tid] + s_out[3][tid];
        float o = fmaf(wc0[ti], pw0, fmaf(wc1[ti], pw1, r + pbv));
        orow[(size_t)ti*DIM + tid] = o;
    }
}

extern "C" void kernel_launch(void* const* d_in, const int* in_sizes, int n_in,
                              void* d_out, int out_size, void* d_ws, size_t ws_size,
                              hipStream_t stream)
{
    const float* Tg    = (const float*)d_in[0];
    const float* dur   = (const float*)d_in[1];
    const float* feat  = (const float*)d_in[2];
    const float* c1w   = (const float*)d_in[3];
    const float* c1b   = (const float*)d_in[4];
    const float* bn1g  = (const float*)d_in[5];
    const float* bn1b  = (const float*)d_in[6];
    const float* bn1m  = (const float*)d_in[7];
    const float* bn1v  = (const float*)d_in[8];
    const float* c2w   = (const float*)d_in[9];
    const float* c2b   = (const float*)d_in[10];
    const float* bn2g  = (const float*)d_in[11];
    const float* bn2b  = (const float*)d_in[12];
    const float* bn2m  = (const float*)d_in[13];
    const float* bn2v  = (const float*)d_in[14];
    const float* sb1w1 = (const float*)d_in[15];
    const float* sb1b1 = (const float*)d_in[16];
    const float* sb1w2 = (const float*)d_in[17];
    const float* sb1b2 = (const float*)d_in[18];
    const float* sb2w1 = (const float*)d_in[19];
    const float* sb2b1 = (const float*)d_in[20];
    const float* sb2w2 = (const float*)d_in[21];
    const float* sb2b2 = (const float*)d_in[22];
    const float* p1w   = (const float*)d_in[23];
    const float* p1b   = (const float*)d_in[24];
    const float* p2w   = (const float*)d_in[25];
    const float* p2b   = (const float*)d_in[26];
    float* out = (float*)d_out;

    // workspace layout (floats): ts[4096] | te[4096] | v1[8192] | v2[65536]
    float* ws = (float*)d_ws;
    float* ts = ws;
    float* te = ws + 4096;
    float* v1 = ws + 8192;
    float* v2 = ws + 16384;

    cumsum_k<<<NN, WT, 0, stream>>>(dur, ts, te);
    prep_k<<<dim3(WT, NN), 256, 0, stream>>>(feat, c1w, c1b, bn1g, bn1b, bn1m, bn1v,
                                             c2w, c2b, bn2g, bn2b, bn2m, bn2v,
                                             sb1w1, sb1b1, sb2w1, sb2b1, ts, te, v1, v2);
    main_k<<<dim3(TT/TBT, NN), 256, 0, stream>>>(Tg, feat, v1, v2,
                                                 sb1w1, sb1w2, sb1b2,
                                                 sb2w1, sb2w2, sb2b2,
                                                 p1w, p1b, p2w, p2b, out);
}